// Round 5
// baseline (3119.825 us; speedup 1.0000x reference)
//
#include <hip/hip_runtime.h>
#include <hip/hip_bf16.h>
#include <math.h>

#define HID 256
#define BSZ 64
#define TLEN 256
#define INW 64
#define OUTW 32
#define NOISE_STD 0.05f
#define TAU 0.2f
#define SENT 0xFFFFFFFFFFFFFFFFull

typedef __attribute__((ext_vector_type(8))) short short8;
typedef __attribute__((ext_vector_type(4))) short shortx4;
typedef __attribute__((ext_vector_type(4))) float floatx4;
typedef unsigned long long u64;

// LDS layout for r: [b][k], 8-short-granule XOR swizzle (R0-proven).
// Fill (fixed b, lanes span k): 32 banks, same-dword pairs merge -> free.
// A-frag b128 (8 consecutive k): uniform over bank groups -> minimum.
__device__ __forceinline__ int ridx(int b, int k) {
    int P = ((b >> 2) & 7) ^ ((b & 3) << 1);
    return b * 256 + ((((k >> 3) ^ P) & 31) << 3) + (k & 7);
}

// ---------------------------------------------------------------------------
// one-time: W [j][i][k] fp32 -> bf16 in MFMA B-fragment order
//   Wsw[(((j*8+kk)*16+ni)*64+l)*8 + e] = W[j][ni*16+(l&15)][kk*32+(l>>4)*8+e]
// ---------------------------------------------------------------------------
__global__ __launch_bounds__(256) void swizzle_kernel(const float* __restrict__ W,
                                                      __hip_bfloat16* __restrict__ Wsw) {
    int g = blockIdx.x * 256 + threadIdx.x;      // 0 .. 2^21-1
    int l  = g & 63;
    int ni = (g >> 6) & 15;
    int kk = (g >> 10) & 7;
    int j  = g >> 13;
    int i  = ni * 16 + (l & 15);
    int k0 = kk * 32 + (l >> 4) * 8;
    const float* __restrict__ src = W + ((size_t)j * HID + i) * HID + k0;
    __hip_bfloat16* __restrict__ dst = Wsw + (size_t)g * 8;
#pragma unroll
    for (int e = 0; e < 8; ++e) dst[e] = __float2bfloat16(src[e]);
}

// ---------------------------------------------------------------------------
// init: ring slot 0: ring0[g*256+k] = pack4(bf16(tanh(x0[4g+e][k])))
// grid = 16 blocks (g), 256 threads (k)
// ---------------------------------------------------------------------------
__global__ __launch_bounds__(256) void init_kernel(const float* __restrict__ x0,
                                                   u64* __restrict__ ring0) {
    int g = blockIdx.x;          // 0..15
    int k = threadIdx.x;
    u64 v = 0;
#pragma unroll
    for (int e = 0; e < 4; ++e) {
        __hip_bfloat16 h = __float2bfloat16(tanhf(x0[(4 * g + e) * HID + k]));
        v |= (u64)(*(unsigned short*)&h) << (16 * e);
    }
    ring0[g * 256 + k] = v;
}

// ---------------------------------------------------------------------------
// one-time: pre[t][j][b] = NOISE_STD*noise[t][b][j]
//                        + TAU*(w_in_b[j] + sum_in u[b][t][in]*w_in_w[j][in])
// ---------------------------------------------------------------------------
__global__ __launch_bounds__(256) void pre_kernel(const float* __restrict__ u,
                                                  const float* __restrict__ w_in_w,
                                                  const float* __restrict__ w_in_b,
                                                  const float* __restrict__ noise,
                                                  float* __restrict__ pre) {
    __shared__ float ulds[BSZ][INW + 4];
    const int t = blockIdx.x;
    const int j = threadIdx.x;
    {
        int b = threadIdx.x >> 2, q = threadIdx.x & 3;
#pragma unroll
        for (int e = 0; e < 4; ++e) {
            float4 v = *(const float4*)(u + ((size_t)b * TLEN + t) * INW + q * 16 + e * 4);
            *(float4*)&ulds[b][q * 16 + e * 4] = v;
        }
    }
    float wreg[INW];
#pragma unroll
    for (int q = 0; q < INW / 4; ++q) {
        float4 v = *(const float4*)(w_in_w + (size_t)j * INW + q * 4);
        wreg[q * 4 + 0] = v.x; wreg[q * 4 + 1] = v.y;
        wreg[q * 4 + 2] = v.z; wreg[q * 4 + 3] = v.w;
    }
    float bias = w_in_b[j];
    __syncthreads();
    for (int b = 0; b < BSZ; ++b) {
        float s = bias;
#pragma unroll
        for (int in_ = 0; in_ < INW; ++in_) s = fmaf(ulds[b][in_], wreg[in_], s);
        float nz = noise[((size_t)t * BSZ + b) * HID + j];
        pre[((size_t)t * HID + j) * BSZ + b] = NOISE_STD * nz + TAU * s;
    }
}

// ---------------------------------------------------------------------------
// persistent kernel — R3 compute structure (verified 1278us) + spec-load
// protocol over a 3-slot ring:
//  - consumer step t: issue 16 coalesced spec loads of slot t%3 column tid
//    FIRST (overlaps pre[] prefetch and flag poll); poll 4B flag >= t; then
//    reload only cells still == SENT (guaranteed fresh: producer drains
//    before flag). Steady state: data already arrived -> saves the data RT.
//  - 3 slots make spec loads race-free: flag >= t-1 (observed before step t
//    starts) causally implies slot t%3 was poisoned before any republish,
//    so spec values are in {SENT, r_t}, never stale r_{t-3}.
//  - wave0 poisons own column of slot (t+2)%3 right after barrier B (guard:
//    all flags >= t -> all step-(t-1) readers done); tail vmcnt(0) orders
//    poison+publish before flag.
//  - w_hh folded into MFMA acc init (each wave owns its i-range).
// ---------------------------------------------------------------------------
__global__ __launch_bounds__(256, 1) void persist_kernel(
    const __hip_bfloat16* __restrict__ Wsw,
    const float* __restrict__ w_hh,
    const float* __restrict__ u,              // fallbacks
    const float* __restrict__ w_in_w,
    const float* __restrict__ w_in_b,
    const float* __restrict__ noise,
    const float* __restrict__ x0,
    u64* __restrict__ ring,                   // [3][16][256] u64 packets
    float* __restrict__ traj,                 // [B][T][HID] (fallback path)
    float* __restrict__ trajWS,               // [T][HID][B] (fast path)
    float* __restrict__ xfinal,
    int* __restrict__ ready,                  // 256 flags, 64B apart (zeroed)
    const float* __restrict__ pre,            // [T][HID][B] or unused
    int use_pre, int use_tws) {
    __shared__ short rlds[16384];             // 32 KB swizzled r
    __shared__ float redw[256];
    __shared__ char lds_pad[57344];           // force 1 block/CU (total ~90 KB)

    const int tid  = threadIdx.x;
    const int j    = blockIdx.x;
    const int w    = tid >> 6;
    const int lane = tid & 63;
    const int quad = lane >> 4;
    const int col  = lane & 15;

    if (j == 0x7fffffff) lds_pad[tid] = 0;    // never true; keeps pad alive

    // ---- W fragments into registers: 32 x short8 = 128 VGPRs.
    //      Lane mapping W[j, i=tile+(l&15), k=(l>>4)*8+e] serves as the
    //      A-operand (m=i) of the swapped MFMA (A/B frag layouts identical).
    short8 wreg[32];
    {
        const short* __restrict__ wsh = (const short*)Wsw;
#pragma unroll
        for (int kk = 0; kk < 8; ++kk)
#pragma unroll
            for (int mt = 0; mt < 4; ++mt)
                wreg[kk * 4 + mt] = *(const short8*)(wsh +
                    ((((size_t)j * 8 + kk) * 16 + (w * 4 + mt)) * 64 + lane) * 8);
    }
    // whh for this thread's 16 i-values: i = (w*4+mt)*16 + quad*4 + rg
    // (folded into MFMA acc init; each wave owns its i-range exclusively)
    float whh16[16];
#pragma unroll
    for (int mt = 0; mt < 4; ++mt)
#pragma unroll
        for (int rg = 0; rg < 4; ++rg)
            whh16[mt * 4 + rg] = w_hh[j * HID + (w * 4 + mt) * 16 + quad * 4 + rg];

    float xb = 0.f;
    if (tid < BSZ) xb = x0[tid * HID + j];

#pragma unroll 1
    for (int t = 0; t < TLEN; ++t) {
        const u64* __restrict__ rslot = ring + (size_t)(t % 3) * 4096;
        u64* __restrict__ wslot = ring + (size_t)((t + 1) % 3) * 4096;

        // ---- speculative data loads FIRST (own column, coalesced) ----
        u64 v[16];
#pragma unroll
        for (int g = 0; g < 16; ++g)
            v[g] = __hip_atomic_load(rslot + g * 256 + tid, __ATOMIC_RELAXED,
                                     __HIP_MEMORY_SCOPE_AGENT);

        // ---- input term prefetch (independent, overlaps poll) ----
        float extra = 0.f;
        if (tid < BSZ) {
            if (use_pre) {
                extra = pre[((size_t)t * HID + j) * BSZ + tid];
            } else {
                float isum = w_in_b[j];
                const float4* __restrict__ urow =
                    (const float4*)(u + ((size_t)tid * TLEN + t) * INW);
                const float4* __restrict__ wrow = (const float4*)(w_in_w + (size_t)j * INW);
#pragma unroll
                for (int q = 0; q < INW / 4; ++q) {
                    float4 uu = urow[q], ww = wrow[q];
                    isum = fmaf(uu.x, ww.x, isum);
                    isum = fmaf(uu.y, ww.y, isum);
                    isum = fmaf(uu.z, ww.z, isum);
                    isum = fmaf(uu.w, ww.w, isum);
                }
                float nz = noise[((size_t)t * BSZ + tid) * HID + j];
                extra = NOISE_STD * nz + TAU * isum;
            }
        }

        // ---- thread-local wait + sentinel validation ----
        if (t > 0) {
            while (__hip_atomic_load(ready + tid * 16, __ATOMIC_RELAXED,
                                     __HIP_MEMORY_SCOPE_AGENT) < t)
                __builtin_amdgcn_s_sleep(1);
            asm volatile("" ::: "memory");
            // flag >= t: publish landed (drain-before-flag) -> one reload of
            // any SENT cell returns fresh data; loop is a safety net.
            int pend = 1;
            while (pend) {
                pend = 0;
#pragma unroll
                for (int g = 0; g < 16; ++g)
                    if (v[g] == SENT) {
                        v[g] = __hip_atomic_load(rslot + g * 256 + tid,
                                                 __ATOMIC_RELAXED,
                                                 __HIP_MEMORY_SCOPE_AGENT);
                        pend |= (v[g] == SENT);
                    }
            }
        }

        // ---- fill rlds (R0-proven pattern) ----
#pragma unroll
        for (int g = 0; g < 16; ++g)
#pragma unroll
            for (int e = 0; e < 4; ++e)
                rlds[ridx(4 * g + e, tid)] = (short)(v[g] >> (16 * e));
        __syncthreads();                       // barrier B: rlds complete

        // ---- poison own column of slot t+2 (guard: all flags >= t seen at
        //      barrier B -> all step-(t-1) readers done; tail drain orders
        //      poison before flag) ----
        if (w == 0 && lane < 16)
            __hip_atomic_store(ring + (size_t)((t + 2) % 3) * 4096 + lane * 256 + j,
                               SENT, __ATOMIC_RELAXED, __HIP_MEMORY_SCOPE_AGENT);

        // ---- GEMM (swapped): D[i,b] = w_hh[j,i] + sum_k W[j,i,k] r[b,k] ----
        floatx4 acc[4][4];                     // acc[mt=i-tile][nt=b-tile]
#pragma unroll
        for (int mt = 0; mt < 4; ++mt)
#pragma unroll
            for (int nt = 0; nt < 4; ++nt)
                acc[mt][nt] = (floatx4){whh16[mt * 4 + 0], whh16[mt * 4 + 1],
                                        whh16[mt * 4 + 2], whh16[mt * 4 + 3]};

#pragma unroll
        for (int kk = 0; kk < 8; ++kk) {
            short8 afrag[4];
#pragma unroll
            for (int nt = 0; nt < 4; ++nt)
                afrag[nt] = *(const short8*)&rlds[ridx(nt * 16 + col, kk * 32 + quad * 8)];
#pragma unroll
            for (int mt = 0; mt < 4; ++mt)
#pragma unroll
                for (int nt = 0; nt < 4; ++nt)
                    acc[mt][nt] = __builtin_amdgcn_mfma_f32_16x16x32_bf16(
                        wreg[kk * 4 + mt], afrag[nt], acc[mt][nt], 0, 0, 0);
        }

        // ---- epilogue: part[b] = sum_i r[b,i]*P'[i,b] ----
        // lane (col,quad): acc[mt][nt][rg] = P'[i=(w*4+mt)*16+quad*4+rg][b=nt*16+col]
        float part[4];
#pragma unroll
        for (int nt = 0; nt < 4; ++nt) part[nt] = 0.f;
#pragma unroll
        for (int mt = 0; mt < 4; ++mt) {
            const int ib = (w * 4 + mt) * 16 + quad * 4;
#pragma unroll
            for (int nt = 0; nt < 4; ++nt) {
                const int b = nt * 16 + col;
                shortx4 r4 = *(const shortx4*)&rlds[ridx(b, ib)];
#pragma unroll
                for (int rg = 0; rg < 4; ++rg) {
                    short rs = r4[rg];
                    float rv = __bfloat162float(*(__hip_bfloat16*)&rs);
                    part[nt] = fmaf(rv, acc[mt][nt][rg], part[nt]);
                }
            }
        }
        // reduce across quads only: 8 shuffles
#pragma unroll
        for (int nt = 0; nt < 4; ++nt) {
            part[nt] += __shfl_xor(part[nt], 16, 64);
            part[nt] += __shfl_xor(part[nt], 32, 64);
        }
        if (quad == 0) {
#pragma unroll
            for (int nt = 0; nt < 4; ++nt)
                redw[w * 64 + nt * 16 + col] = part[nt];
        }
        __syncthreads();                       // barrier C: redw complete

        // ---- wave 0: state update, publish, trajectory ----
        if (w == 0) {
            const int b = lane;
            float rec = redw[b] + redw[64 + b] + redw[128 + b] + redw[192 + b];
            float xn = xb + extra + TAU * (rec - xb);
            xb = xn;

            if (t < TLEN - 1) {
                __hip_bfloat16 h = __float2bfloat16(tanhf(xn));
                int hs = (int)(*(unsigned short*)&h);
                int src = 4 * (lane & 15);
                u64 pv = (u64)(unsigned)__shfl(hs, src + 0, 64)
                       | ((u64)(unsigned)__shfl(hs, src + 1, 64) << 16)
                       | ((u64)(unsigned)__shfl(hs, src + 2, 64) << 32)
                       | ((u64)(unsigned)__shfl(hs, src + 3, 64) << 48);
                if (lane < 16)
                    __hip_atomic_store(wslot + (size_t)lane * 256 + j, pv,
                                       __ATOMIC_RELAXED, __HIP_MEMORY_SCOPE_AGENT);
                asm volatile("s_waitcnt vmcnt(0)" ::: "memory");   // drain data+poison
                if (lane == 0)
                    __hip_atomic_store(ready + j * 16, t + 1, __ATOMIC_RELAXED,
                                       __HIP_MEMORY_SCOPE_AGENT);
            }

            if (use_tws) {
                trajWS[((size_t)t * HID + j) * BSZ + b] = xn;      // 256B coalesced
            } else {
                traj[((size_t)b * TLEN + t) * HID + j] = xn;
                if (t == TLEN - 1) xfinal[b * HID + j] = xn;
            }
        }
    }
}

// ---------------------------------------------------------------------------
// fused transpose + output (fast path). block = t.
// ---------------------------------------------------------------------------
__global__ __launch_bounds__(256) void fixup_kernel(
    const float* __restrict__ trajWS,   // [T][HID][B]
    const float* __restrict__ w_out_w,  // [OUT][HID]
    const float* __restrict__ w_out_b,  // [OUT]
    float* __restrict__ traj,           // [B][T][HID]
    float* __restrict__ xfinal,         // [B][HID]
    float* __restrict__ out) {          // [B][T][OUT]
    __shared__ float xv[BSZ * 257];
    __shared__ float wol[OUTW * 257];
    const int t = blockIdx.x, tid = threadIdx.x;

#pragma unroll
    for (int it = 0; it < 16; ++it) {
        int flat = it * 1024 + tid * 4;          // j*64 + b
        float4 v = *(const float4*)(trajWS + (size_t)t * 16384 + flat);
        int jj = flat >> 6, b = flat & 63;
        xv[(b + 0) * 257 + jj] = v.x;
        xv[(b + 1) * 257 + jj] = v.y;
        xv[(b + 2) * 257 + jj] = v.z;
        xv[(b + 3) * 257 + jj] = v.w;
    }
#pragma unroll
    for (int it = 0; it < 8; ++it) {
        int flat = it * 1024 + tid * 4;          // o*256 + h
        float4 v = *(const float4*)(w_out_w + flat);
        int o = flat >> 8, h = flat & 255;
        *(float4*)&wol[o * 257 + h] = v;
    }
    __syncthreads();

    for (int b = 0; b < BSZ; ++b)
        traj[((size_t)b * TLEN + t) * HID + tid] = xv[b * 257 + tid];
    if (t == TLEN - 1)
        for (int b = 0; b < BSZ; ++b)
            xfinal[b * HID + tid] = xv[b * 257 + tid];

    __syncthreads();
#pragma unroll
    for (int it = 0; it < 64; ++it)
        xv[it * 257 + tid] = tanhf(xv[it * 257 + tid]);
    __syncthreads();

    const int o = tid & 31;
    const float bias = w_out_b[o];
#pragma unroll 1
    for (int rep = 0; rep < 8; ++rep) {
        int b = rep * 8 + (tid >> 5);
        float s = bias;
#pragma unroll 8
        for (int h = 0; h < HID; ++h)
            s = fmaf(xv[b * 257 + h], wol[o * 257 + h], s);
        out[((size_t)b * TLEN + t) * OUTW + o] = s;
    }
}

// ---------------------------------------------------------------------------
// fallback output kernel — used when ws too small
// ---------------------------------------------------------------------------
__global__ __launch_bounds__(256) void output_kernel(
    const float* __restrict__ traj, const float* __restrict__ w_out_w,
    const float* __restrict__ w_out_b, float* __restrict__ out) {
    __shared__ float th[8][HID + 1];
    const int bt0 = blockIdx.x * 8;
    const int tid = threadIdx.x;
#pragma unroll
    for (int m = 0; m < 8; ++m) {
        int idx = m * 256 + tid;
        th[idx >> 8][idx & 255] = tanhf(traj[(size_t)bt0 * HID + idx]);
    }
    __syncthreads();
    const int row = tid >> 5, o = tid & 31;
    const float* __restrict__ wrow = w_out_w + (size_t)o * HID;
    float s = w_out_b[o];
#pragma unroll 8
    for (int h = 0; h < HID; ++h) s = fmaf(th[row][h], wrow[h], s);
    out[(size_t)(bt0 + row) * OUTW + o] = s;
}

// ---------------------------------------------------------------------------
extern "C" void kernel_launch(void* const* d_in, const int* in_sizes, int n_in,
                              void* d_out, int out_size, void* d_ws, size_t ws_size,
                              hipStream_t stream) {
    const float* u       = (const float*)d_in[0];
    const float* x0      = (const float*)d_in[1];
    const float* noise   = (const float*)d_in[2];
    const float* w_hh    = (const float*)d_in[3];
    const float* W       = (const float*)d_in[4];
    const float* w_in_w  = (const float*)d_in[5];
    const float* w_in_b  = (const float*)d_in[6];
    const float* w_out_w = (const float*)d_in[7];
    const float* w_out_b = (const float*)d_in[8];

    float* out    = (float*)d_out;                     // [B][T][OUT]
    float* xfinal = out + (size_t)BSZ * TLEN * OUTW;
    float* traj   = xfinal + (size_t)BSZ * HID;

    // ws layout: Wsw 33.5M | ring 96K (3 x [16][256] u64) | flags 16K
    //          | trajWS 16.7M | pre 16.7M
    char* ws = (char*)d_ws;
    __hip_bfloat16* Wsw = (__hip_bfloat16*)ws;
    u64*   ring = (u64*)(ws + 33554432);
    int*   rdy  = (int*)(ws + 33652736);
    float* tws  = (float*)(ws + 33669120);
    float* pre  = (float*)(ws + 50446336);
    const size_t NEED_TWS = 50446336ull;
    const size_t NEED_PRE = 67223552ull;
    const int use_tws = (ws_size >= NEED_TWS) ? 1 : 0;
    const int use_pre = (ws_size >= NEED_PRE) ? 1 : 0;

    hipMemsetAsync(rdy, 0, 16384, stream);
    // poison ring slots 1,2 (slot 0 gets real init data)
    hipMemsetAsync((char*)ring + 32768, 0xFF, 65536, stream);
    swizzle_kernel<<<8192, 256, 0, stream>>>(W, Wsw);
    init_kernel<<<16, 256, 0, stream>>>(x0, ring);
    if (use_pre)
        pre_kernel<<<TLEN, 256, 0, stream>>>(u, w_in_w, w_in_b, noise, pre);

    persist_kernel<<<256, 256, 0, stream>>>(
        Wsw, w_hh, u, w_in_w, w_in_b, noise, x0,
        ring, traj, tws, xfinal, rdy, pre, use_pre, use_tws);

    if (use_tws)
        fixup_kernel<<<TLEN, 256, 0, stream>>>(tws, w_out_w, w_out_b, traj, xfinal, out);
    else
        output_kernel<<<(BSZ * TLEN) / 8, 256, 0, stream>>>(traj, w_out_w, w_out_b, out);
}

// Round 6
// 1529.317 us; speedup vs baseline: 2.0400x; 2.0400x over previous
//
#include <hip/hip_runtime.h>
#include <hip/hip_bf16.h>
#include <math.h>

#define HID 256
#define BSZ 64
#define TLEN 256
#define INW 64
#define OUTW 32
#define NOISE_STD 0.05f
#define TAU 0.2f

typedef __attribute__((ext_vector_type(8))) short short8;
typedef __attribute__((ext_vector_type(4))) short shortx4;
typedef __attribute__((ext_vector_type(4))) float floatx4;
typedef unsigned long long u64;

// LDS layout for r: [b][k], 8-short-granule XOR swizzle (R0-proven).
// Fill (fixed b, lanes span k): 32 banks, same-dword pairs merge -> free.
// A-frag b128 (8 consecutive k): uniform over bank groups -> minimum.
__device__ __forceinline__ int ridx(int b, int k) {
    int P = ((b >> 2) & 7) ^ ((b & 3) << 1);
    return b * 256 + ((((k >> 3) ^ P) & 31) << 3) + (k & 7);
}

// ---------------------------------------------------------------------------
// one-time: W [j][i][k] fp32 -> bf16 in MFMA B-fragment order
//   Wsw[(((j*8+kk)*16+ni)*64+l)*8 + e] = W[j][ni*16+(l&15)][kk*32+(l>>4)*8+e]
// ---------------------------------------------------------------------------
__global__ __launch_bounds__(256) void swizzle_kernel(const float* __restrict__ W,
                                                      __hip_bfloat16* __restrict__ Wsw) {
    int g = blockIdx.x * 256 + threadIdx.x;      // 0 .. 2^21-1
    int l  = g & 63;
    int ni = (g >> 6) & 15;
    int kk = (g >> 10) & 7;
    int j  = g >> 13;
    int i  = ni * 16 + (l & 15);
    int k0 = kk * 32 + (l >> 4) * 8;
    const float* __restrict__ src = W + ((size_t)j * HID + i) * HID + k0;
    __hip_bfloat16* __restrict__ dst = Wsw + (size_t)g * 8;
#pragma unroll
    for (int e = 0; e < 8; ++e) dst[e] = __float2bfloat16(src[e]);
}

// ---------------------------------------------------------------------------
// init: buf0[g*256+k] = pack4(bf16(tanh(x0[4g+e][k])))   (transposed packets)
// grid = 16 blocks (g), 256 threads (k)
// ---------------------------------------------------------------------------
__global__ __launch_bounds__(256) void init_kernel(const float* __restrict__ x0,
                                                   u64* __restrict__ buf0) {
    int g = blockIdx.x;          // 0..15
    int k = threadIdx.x;
    u64 v = 0;
#pragma unroll
    for (int e = 0; e < 4; ++e) {
        __hip_bfloat16 h = __float2bfloat16(tanhf(x0[(4 * g + e) * HID + k]));
        v |= (u64)(*(unsigned short*)&h) << (16 * e);
    }
    buf0[g * 256 + k] = v;
}

// ---------------------------------------------------------------------------
// one-time: pre[t][j][b] = NOISE_STD*noise[t][b][j]
//                        + TAU*(w_in_b[j] + sum_in u[b][t][in]*w_in_w[j][in])
// ---------------------------------------------------------------------------
__global__ __launch_bounds__(256) void pre_kernel(const float* __restrict__ u,
                                                  const float* __restrict__ w_in_w,
                                                  const float* __restrict__ w_in_b,
                                                  const float* __restrict__ noise,
                                                  float* __restrict__ pre) {
    __shared__ float ulds[BSZ][INW + 4];
    const int t = blockIdx.x;
    const int j = threadIdx.x;
    {
        int b = threadIdx.x >> 2, q = threadIdx.x & 3;
#pragma unroll
        for (int e = 0; e < 4; ++e) {
            float4 v = *(const float4*)(u + ((size_t)b * TLEN + t) * INW + q * 16 + e * 4);
            *(float4*)&ulds[b][q * 16 + e * 4] = v;
        }
    }
    float wreg[INW];
#pragma unroll
    for (int q = 0; q < INW / 4; ++q) {
        float4 v = *(const float4*)(w_in_w + (size_t)j * INW + q * 4);
        wreg[q * 4 + 0] = v.x; wreg[q * 4 + 1] = v.y;
        wreg[q * 4 + 2] = v.z; wreg[q * 4 + 3] = v.w;
    }
    float bias = w_in_b[j];
    __syncthreads();
    for (int b = 0; b < BSZ; ++b) {
        float s = bias;
#pragma unroll
        for (int in_ = 0; in_ < INW; ++in_) s = fmaf(ulds[b][in_], wreg[in_], s);
        float nz = noise[((size_t)t * BSZ + b) * HID + j];
        pre[((size_t)t * HID + j) * BSZ + b] = NOISE_STD * nz + TAU * s;
    }
}

// ---------------------------------------------------------------------------
// persistent kernel — R3 structure (verified 1278us) + k-half split pipeline:
//  - protocol FROZEN (R0 flags + drain): thread owns column kL=tid&127,
//    half-of-g gb=(tid>>7)*8; waits flag[kL], fills low, B1.
//  - flag[kH] load issued BEFORE GEMM kk0 (RT hides under MFMAs); high data
//    loads issued after check, hide under GEMM kk2-3; fill high; B2;
//    GEMM kk4-7. Between B1 and B2 all writes are high columns, all MFMA
//    reads are low columns -> race-free.
//  - w_hh folded into MFMA acc init (proved correct in R5).
//  - swapped-MFMA epilogue (R3): 16 ds_read_b64, 8 shuffles.
// ---------------------------------------------------------------------------
__global__ __launch_bounds__(256, 1) void persist_kernel(
    const __hip_bfloat16* __restrict__ Wsw,
    const float* __restrict__ w_hh,
    const float* __restrict__ u,              // fallbacks
    const float* __restrict__ w_in_w,
    const float* __restrict__ w_in_b,
    const float* __restrict__ noise,
    const float* __restrict__ x0,
    u64* __restrict__ buf0,                   // [16][256] packets (t even reads)
    u64* __restrict__ buf1,                   // (t odd reads)
    float* __restrict__ traj,                 // [B][T][HID] (fallback path)
    float* __restrict__ trajWS,               // [T][HID][B] (fast path)
    float* __restrict__ xfinal,
    int* __restrict__ ready,                  // 256 flags, 64B apart (zeroed)
    const float* __restrict__ pre,            // [T][HID][B] or unused
    int use_pre, int use_tws) {
    __shared__ short rlds[16384];             // 32 KB swizzled r
    __shared__ float redw[256];

    const int tid  = threadIdx.x;
    const int j    = blockIdx.x;
    const int w    = tid >> 6;
    const int lane = tid & 63;
    const int quad = lane >> 4;
    const int col  = lane & 15;
    const int kL   = tid & 127;               // low column owned
    const int kH   = kL + 128;                // high column owned
    const int gb   = (tid >> 7) * 8;          // packet half: 0 or 8

    // ---- W fragments into registers: 32 x short8 = 128 VGPRs.
    //      Lane mapping W[j, i=tile+(l&15), k=(l>>4)*8+e] serves as the
    //      A-operand (m=i) of the swapped MFMA (A/B frag layouts identical).
    short8 wreg[32];
    {
        const short* __restrict__ wsh = (const short*)Wsw;
#pragma unroll
        for (int kk = 0; kk < 8; ++kk)
#pragma unroll
            for (int mt = 0; mt < 4; ++mt)
                wreg[kk * 4 + mt] = *(const short8*)(wsh +
                    ((((size_t)j * 8 + kk) * 16 + (w * 4 + mt)) * 64 + lane) * 8);
    }
    // whh for this thread's 16 i-values: i = (w*4+mt)*16 + quad*4 + rg
    // (folded into MFMA acc init; each wave owns its i-range exclusively)
    float whh16[16];
#pragma unroll
    for (int mt = 0; mt < 4; ++mt)
#pragma unroll
        for (int rg = 0; rg < 4; ++rg)
            whh16[mt * 4 + rg] = w_hh[j * HID + (w * 4 + mt) * 16 + quad * 4 + rg];

    float xb = 0.f;
    if (tid < BSZ) xb = x0[tid * HID + j];

#pragma unroll 1
    for (int t = 0; t < TLEN; ++t) {
        const u64* __restrict__ rcur = (t & 1) ? buf1 : buf0;
        u64* __restrict__ rnxt = (t & 1) ? buf0 : buf1;

        // ---- input term prefetch (independent, overlaps poll) ----
        float extra = 0.f;
        if (tid < BSZ) {
            if (use_pre) {
                extra = pre[((size_t)t * HID + j) * BSZ + tid];
            } else {
                float isum = w_in_b[j];
                const float4* __restrict__ urow =
                    (const float4*)(u + ((size_t)tid * TLEN + t) * INW);
                const float4* __restrict__ wrow = (const float4*)(w_in_w + (size_t)j * INW);
#pragma unroll
                for (int q = 0; q < INW / 4; ++q) {
                    float4 uu = urow[q], ww = wrow[q];
                    isum = fmaf(uu.x, ww.x, isum);
                    isum = fmaf(uu.y, ww.y, isum);
                    isum = fmaf(uu.z, ww.z, isum);
                    isum = fmaf(uu.w, ww.w, isum);
                }
                float nz = noise[((size_t)t * BSZ + tid) * HID + j];
                extra = NOISE_STD * nz + TAU * isum;
            }
        }

        // ---- low half: wait flag[kL], load 8 packets, fill ----
        if (t > 0) {
            while (__hip_atomic_load(ready + kL * 16, __ATOMIC_RELAXED,
                                     __HIP_MEMORY_SCOPE_AGENT) < t)
                __builtin_amdgcn_s_sleep(1);
            asm volatile("" ::: "memory");
        }
        {
            u64 vl[8];
#pragma unroll
            for (int gg = 0; gg < 8; ++gg)
                vl[gg] = __hip_atomic_load(rcur + (gb + gg) * 256 + kL,
                                           __ATOMIC_RELAXED, __HIP_MEMORY_SCOPE_AGENT);
#pragma unroll
            for (int gg = 0; gg < 8; ++gg)
#pragma unroll
                for (int e = 0; e < 4; ++e)
                    rlds[ridx(4 * (gb + gg) + e, kL)] = (short)(vl[gg] >> (16 * e));
        }
        __syncthreads();                       // barrier B1: low half ready

        // ---- GEMM acc init carries w_hh ----
        floatx4 acc[4][4];                     // acc[mt=i-tile][nt=b-tile]
#pragma unroll
        for (int mt = 0; mt < 4; ++mt)
#pragma unroll
            for (int nt = 0; nt < 4; ++nt)
                acc[mt][nt] = (floatx4){whh16[mt * 4 + 0], whh16[mt * 4 + 1],
                                        whh16[mt * 4 + 2], whh16[mt * 4 + 3]};

        // high flag load issued before MFMAs (RT hides under kk0-1)
        int fh = t;
        if (t > 0)
            fh = __hip_atomic_load(ready + kH * 16, __ATOMIC_RELAXED,
                                   __HIP_MEMORY_SCOPE_AGENT);

        // ---- GEMM kk0-1 (low k) ----
#pragma unroll
        for (int kk = 0; kk < 2; ++kk) {
            short8 afrag[4];
#pragma unroll
            for (int nt = 0; nt < 4; ++nt)
                afrag[nt] = *(const short8*)&rlds[ridx(nt * 16 + col, kk * 32 + quad * 8)];
#pragma unroll
            for (int mt = 0; mt < 4; ++mt)
#pragma unroll
                for (int nt = 0; nt < 4; ++nt)
                    acc[mt][nt] = __builtin_amdgcn_mfma_f32_16x16x32_bf16(
                        wreg[kk * 4 + mt], afrag[nt], acc[mt][nt], 0, 0, 0);
        }

        // ---- high half: confirm flag, issue data loads ----
        if (t > 0 && fh < t) {
            do {
                __builtin_amdgcn_s_sleep(1);
                fh = __hip_atomic_load(ready + kH * 16, __ATOMIC_RELAXED,
                                       __HIP_MEMORY_SCOPE_AGENT);
            } while (fh < t);
        }
        asm volatile("" ::: "memory");
        u64 vh[8];
#pragma unroll
        for (int gg = 0; gg < 8; ++gg)
            vh[gg] = __hip_atomic_load(rcur + (gb + gg) * 256 + kH,
                                       __ATOMIC_RELAXED, __HIP_MEMORY_SCOPE_AGENT);

        // ---- GEMM kk2-3 (low k) — hides high data-load RT ----
#pragma unroll
        for (int kk = 2; kk < 4; ++kk) {
            short8 afrag[4];
#pragma unroll
            for (int nt = 0; nt < 4; ++nt)
                afrag[nt] = *(const short8*)&rlds[ridx(nt * 16 + col, kk * 32 + quad * 8)];
#pragma unroll
            for (int mt = 0; mt < 4; ++mt)
#pragma unroll
                for (int nt = 0; nt < 4; ++nt)
                    acc[mt][nt] = __builtin_amdgcn_mfma_f32_16x16x32_bf16(
                        wreg[kk * 4 + mt], afrag[nt], acc[mt][nt], 0, 0, 0);
        }

        // ---- fill high columns (disjoint from low reads above) ----
#pragma unroll
        for (int gg = 0; gg < 8; ++gg)
#pragma unroll
            for (int e = 0; e < 4; ++e)
                rlds[ridx(4 * (gb + gg) + e, kH)] = (short)(vh[gg] >> (16 * e));
        __syncthreads();                       // barrier B2: high half ready

        // ---- GEMM kk4-7 (high k) ----
#pragma unroll
        for (int kk = 4; kk < 8; ++kk) {
            short8 afrag[4];
#pragma unroll
            for (int nt = 0; nt < 4; ++nt)
                afrag[nt] = *(const short8*)&rlds[ridx(nt * 16 + col, kk * 32 + quad * 8)];
#pragma unroll
            for (int mt = 0; mt < 4; ++mt)
#pragma unroll
                for (int nt = 0; nt < 4; ++nt)
                    acc[mt][nt] = __builtin_amdgcn_mfma_f32_16x16x32_bf16(
                        wreg[kk * 4 + mt], afrag[nt], acc[mt][nt], 0, 0, 0);
        }

        // ---- epilogue: part[b] = sum_i r[b,i]*P'[i,b]  (whh already in acc) ----
        float part[4];
#pragma unroll
        for (int nt = 0; nt < 4; ++nt) part[nt] = 0.f;
#pragma unroll
        for (int mt = 0; mt < 4; ++mt) {
            const int ib = (w * 4 + mt) * 16 + quad * 4;
#pragma unroll
            for (int nt = 0; nt < 4; ++nt) {
                const int b = nt * 16 + col;
                shortx4 r4 = *(const shortx4*)&rlds[ridx(b, ib)];
#pragma unroll
                for (int rg = 0; rg < 4; ++rg) {
                    short rs = r4[rg];
                    float rv = __bfloat162float(*(__hip_bfloat16*)&rs);
                    part[nt] = fmaf(rv, acc[mt][nt][rg], part[nt]);
                }
            }
        }
        // reduce across quads only: 8 shuffles
#pragma unroll
        for (int nt = 0; nt < 4; ++nt) {
            part[nt] += __shfl_xor(part[nt], 16, 64);
            part[nt] += __shfl_xor(part[nt], 32, 64);
        }
        if (quad == 0) {
#pragma unroll
            for (int nt = 0; nt < 4; ++nt)
                redw[w * 64 + nt * 16 + col] = part[nt];
        }
        __syncthreads();                       // barrier C: redw complete

        // ---- wave 0: state update, publish, trajectory ----
        if (w == 0) {
            const int b = lane;
            float rec = redw[b] + redw[64 + b] + redw[128 + b] + redw[192 + b];
            float xn = xb + extra + TAU * (rec - xb);
            xb = xn;

            if (t < TLEN - 1) {
                __hip_bfloat16 h = __float2bfloat16(tanhf(xn));
                int hs = (int)(*(unsigned short*)&h);
                int src = 4 * (lane & 15);
                u64 pv = (u64)(unsigned)__shfl(hs, src + 0, 64)
                       | ((u64)(unsigned)__shfl(hs, src + 1, 64) << 16)
                       | ((u64)(unsigned)__shfl(hs, src + 2, 64) << 32)
                       | ((u64)(unsigned)__shfl(hs, src + 3, 64) << 48);
                if (lane < 16)
                    __hip_atomic_store(rnxt + (size_t)lane * 256 + j, pv,
                                       __ATOMIC_RELAXED, __HIP_MEMORY_SCOPE_AGENT);
                asm volatile("s_waitcnt vmcnt(0)" ::: "memory");   // drain data
                if (lane == 0)
                    __hip_atomic_store(ready + j * 16, t + 1, __ATOMIC_RELAXED,
                                       __HIP_MEMORY_SCOPE_AGENT);
            }

            if (use_tws) {
                trajWS[((size_t)t * HID + j) * BSZ + b] = xn;      // 256B coalesced
            } else {
                traj[((size_t)b * TLEN + t) * HID + j] = xn;
                if (t == TLEN - 1) xfinal[b * HID + j] = xn;
            }
        }
    }
}

// ---------------------------------------------------------------------------
// fused transpose + output (fast path). block = t.
// ---------------------------------------------------------------------------
__global__ __launch_bounds__(256) void fixup_kernel(
    const float* __restrict__ trajWS,   // [T][HID][B]
    const float* __restrict__ w_out_w,  // [OUT][HID]
    const float* __restrict__ w_out_b,  // [OUT]
    float* __restrict__ traj,           // [B][T][HID]
    float* __restrict__ xfinal,         // [B][HID]
    float* __restrict__ out) {          // [B][T][OUT]
    __shared__ float xv[BSZ * 257];
    __shared__ float wol[OUTW * 257];
    const int t = blockIdx.x, tid = threadIdx.x;

#pragma unroll
    for (int it = 0; it < 16; ++it) {
        int flat = it * 1024 + tid * 4;          // j*64 + b
        float4 v = *(const float4*)(trajWS + (size_t)t * 16384 + flat);
        int jj = flat >> 6, b = flat & 63;
        xv[(b + 0) * 257 + jj] = v.x;
        xv[(b + 1) * 257 + jj] = v.y;
        xv[(b + 2) * 257 + jj] = v.z;
        xv[(b + 3) * 257 + jj] = v.w;
    }
#pragma unroll
    for (int it = 0; it < 8; ++it) {
        int flat = it * 1024 + tid * 4;          // o*256 + h
        float4 v = *(const float4*)(w_out_w + flat);
        int o = flat >> 8, h = flat & 255;
        *(float4*)&wol[o * 257 + h] = v;
    }
    __syncthreads();

    for (int b = 0; b < BSZ; ++b)
        traj[((size_t)b * TLEN + t) * HID + tid] = xv[b * 257 + tid];
    if (t == TLEN - 1)
        for (int b = 0; b < BSZ; ++b)
            xfinal[b * HID + tid] = xv[b * 257 + tid];

    __syncthreads();
#pragma unroll
    for (int it = 0; it < 64; ++it)
        xv[it * 257 + tid] = tanhf(xv[it * 257 + tid]);
    __syncthreads();

    const int o = tid & 31;
    const float bias = w_out_b[o];
#pragma unroll 1
    for (int rep = 0; rep < 8; ++rep) {
        int b = rep * 8 + (tid >> 5);
        float s = bias;
#pragma unroll 8
        for (int h = 0; h < HID; ++h)
            s = fmaf(xv[b * 257 + h], wol[o * 257 + h], s);
        out[((size_t)b * TLEN + t) * OUTW + o] = s;
    }
}

// ---------------------------------------------------------------------------
// fallback output kernel — used when ws too small
// ---------------------------------------------------------------------------
__global__ __launch_bounds__(256) void output_kernel(
    const float* __restrict__ traj, const float* __restrict__ w_out_w,
    const float* __restrict__ w_out_b, float* __restrict__ out) {
    __shared__ float th[8][HID + 1];
    const int bt0 = blockIdx.x * 8;
    const int tid = threadIdx.x;
#pragma unroll
    for (int m = 0; m < 8; ++m) {
        int idx = m * 256 + tid;
        th[idx >> 8][idx & 255] = tanhf(traj[(size_t)bt0 * HID + idx]);
    }
    __syncthreads();
    const int row = tid >> 5, o = tid & 31;
    const float* __restrict__ wrow = w_out_w + (size_t)o * HID;
    float s = w_out_b[o];
#pragma unroll 8
    for (int h = 0; h < HID; ++h) s = fmaf(th[row][h], wrow[h], s);
    out[(size_t)(bt0 + row) * OUTW + o] = s;
}

// ---------------------------------------------------------------------------
extern "C" void kernel_launch(void* const* d_in, const int* in_sizes, int n_in,
                              void* d_out, int out_size, void* d_ws, size_t ws_size,
                              hipStream_t stream) {
    const float* u       = (const float*)d_in[0];
    const float* x0      = (const float*)d_in[1];
    const float* noise   = (const float*)d_in[2];
    const float* w_hh    = (const float*)d_in[3];
    const float* W       = (const float*)d_in[4];
    const float* w_in_w  = (const float*)d_in[5];
    const float* w_in_b  = (const float*)d_in[6];
    const float* w_out_w = (const float*)d_in[7];
    const float* w_out_b = (const float*)d_in[8];

    float* out    = (float*)d_out;                     // [B][T][OUT]
    float* xfinal = out + (size_t)BSZ * TLEN * OUTW;
    float* traj   = xfinal + (size_t)BSZ * HID;

    // ws layout: Wsw 33.5M | buf0 32K | buf1 32K | flags 16K | trajWS 16.7M | pre 16.7M
    char* ws = (char*)d_ws;
    __hip_bfloat16* Wsw = (__hip_bfloat16*)ws;
    u64*   buf0 = (u64*)(ws + 33554432);
    u64*   buf1 = (u64*)(ws + 33587200);
    int*   rdy  = (int*)(ws + 33619968);
    float* tws  = (float*)(ws + 33636352);
    float* pre  = (float*)(ws + 50413568);
    const size_t NEED_TWS = 50413568ull;
    const size_t NEED_PRE = 67190784ull;
    const int use_tws = (ws_size >= NEED_TWS) ? 1 : 0;
    const int use_pre = (ws_size >= NEED_PRE) ? 1 : 0;

    hipMemsetAsync(rdy, 0, 16384, stream);
    swizzle_kernel<<<8192, 256, 0, stream>>>(W, Wsw);
    init_kernel<<<16, 256, 0, stream>>>(x0, buf0);
    if (use_pre)
        pre_kernel<<<TLEN, 256, 0, stream>>>(u, w_in_w, w_in_b, noise, pre);

    persist_kernel<<<256, 256, 0, stream>>>(
        Wsw, w_hh, u, w_in_w, w_in_b, noise, x0,
        buf0, buf1, traj, tws, xfinal, rdy, pre, use_pre, use_tws);

    if (use_tws)
        fixup_kernel<<<TLEN, 256, 0, stream>>>(tws, w_out_w, w_out_b, traj, xfinal, out);
    else
        output_kernel<<<(BSZ * TLEN) / 8, 256, 0, stream>>>(traj, w_out_w, w_out_b, out);
}

// Round 7
// 1436.746 us; speedup vs baseline: 2.1715x; 1.0644x over previous
//
#include <hip/hip_runtime.h>
#include <hip/hip_bf16.h>
#include <math.h>

#define HID 256
#define BSZ 64
#define TLEN 256
#define INW 64
#define OUTW 32
#define NOISE_STD 0.05f
#define TAU 0.2f

typedef __attribute__((ext_vector_type(8))) short short8;
typedef __attribute__((ext_vector_type(4))) short shortx4;
typedef __attribute__((ext_vector_type(4))) float floatx4;
typedef unsigned long long u64;

// LDS layout for r: [b][k], 8-short-granule XOR swizzle (R0-proven).
// Fill (fixed b, lanes span k): 32 banks, same-dword pairs merge -> free.
// A-frag b128 (8 consecutive k): uniform over bank groups -> minimum.
__device__ __forceinline__ int ridx(int b, int k) {
    int P = ((b >> 2) & 7) ^ ((b & 3) << 1);
    return b * 256 + ((((k >> 3) ^ P) & 31) << 3) + (k & 7);
}

// fast tanh: 1 - 2/(e^{2x}+1). ~10cy vs libm tanhf ~30+. Saturates correctly
// (e->inf => 1, e->0 => -1). |err|~1e-7 << bf16 quantization (2^-8).
__device__ __forceinline__ float fast_tanh(float x) {
    float e = __expf(2.f * x);
    return 1.f - 2.f / (e + 1.f);
}

// ---------------------------------------------------------------------------
// one-time: W [j][i][k] fp32 -> bf16 in MFMA B-fragment order
//   Wsw[(((j*8+kk)*16+ni)*64+l)*8 + e] = W[j][ni*16+(l&15)][kk*32+(l>>4)*8+e]
// ---------------------------------------------------------------------------
__global__ __launch_bounds__(256) void swizzle_kernel(const float* __restrict__ W,
                                                      __hip_bfloat16* __restrict__ Wsw) {
    int g = blockIdx.x * 256 + threadIdx.x;      // 0 .. 2^21-1
    int l  = g & 63;
    int ni = (g >> 6) & 15;
    int kk = (g >> 10) & 7;
    int j  = g >> 13;
    int i  = ni * 16 + (l & 15);
    int k0 = kk * 32 + (l >> 4) * 8;
    const float* __restrict__ src = W + ((size_t)j * HID + i) * HID + k0;
    __hip_bfloat16* __restrict__ dst = Wsw + (size_t)g * 8;
#pragma unroll
    for (int e = 0; e < 8; ++e) dst[e] = __float2bfloat16(src[e]);
}

// ---------------------------------------------------------------------------
// init: buf0[g*256+k] = pack4(bf16(tanh(x0[4g+e][k])))   (transposed packets)
// grid = 16 blocks (g), 256 threads (k)
// ---------------------------------------------------------------------------
__global__ __launch_bounds__(256) void init_kernel(const float* __restrict__ x0,
                                                   u64* __restrict__ buf0) {
    int g = blockIdx.x;          // 0..15
    int k = threadIdx.x;
    u64 v = 0;
#pragma unroll
    for (int e = 0; e < 4; ++e) {
        __hip_bfloat16 h = __float2bfloat16(tanhf(x0[(4 * g + e) * HID + k]));
        v |= (u64)(*(unsigned short*)&h) << (16 * e);
    }
    buf0[g * 256 + k] = v;
}

// ---------------------------------------------------------------------------
// one-time: pre[t][j][b] = NOISE_STD*noise[t][b][j]
//                        + TAU*(w_in_b[j] + sum_in u[b][t][in]*w_in_w[j][in])
// ---------------------------------------------------------------------------
__global__ __launch_bounds__(256) void pre_kernel(const float* __restrict__ u,
                                                  const float* __restrict__ w_in_w,
                                                  const float* __restrict__ w_in_b,
                                                  const float* __restrict__ noise,
                                                  float* __restrict__ pre) {
    __shared__ float ulds[BSZ][INW + 4];
    const int t = blockIdx.x;
    const int j = threadIdx.x;
    {
        int b = threadIdx.x >> 2, q = threadIdx.x & 3;
#pragma unroll
        for (int e = 0; e < 4; ++e) {
            float4 v = *(const float4*)(u + ((size_t)b * TLEN + t) * INW + q * 16 + e * 4);
            *(float4*)&ulds[b][q * 16 + e * 4] = v;
        }
    }
    float wreg[INW];
#pragma unroll
    for (int q = 0; q < INW / 4; ++q) {
        float4 v = *(const float4*)(w_in_w + (size_t)j * INW + q * 4);
        wreg[q * 4 + 0] = v.x; wreg[q * 4 + 1] = v.y;
        wreg[q * 4 + 2] = v.z; wreg[q * 4 + 3] = v.w;
    }
    float bias = w_in_b[j];
    __syncthreads();
    for (int b = 0; b < BSZ; ++b) {
        float s = bias;
#pragma unroll
        for (int in_ = 0; in_ < INW; ++in_) s = fmaf(ulds[b][in_], wreg[in_], s);
        float nz = noise[((size_t)t * BSZ + b) * HID + j];
        pre[((size_t)t * HID + j) * BSZ + b] = NOISE_STD * nz + TAU * s;
    }
}

// ---------------------------------------------------------------------------
// persistent kernel — R3 structure (verified 1278us, protocol FROZEN) +
// three serial-tail/epilogue cuts:
//  - w_hh folded into MFMA acc init (verified R5/R6): -16 epilogue adds
//  - redw stored transposed [b][w]: wave0 rec = one ds_read_b128 (was 4 b32)
//  - fast_tanh on the publish tail (libm tanhf -> exp-based, ~20cy saved)
// ---------------------------------------------------------------------------
__global__ __launch_bounds__(256, 1) void persist_kernel(
    const __hip_bfloat16* __restrict__ Wsw,
    const float* __restrict__ w_hh,
    const float* __restrict__ u,              // fallbacks
    const float* __restrict__ w_in_w,
    const float* __restrict__ w_in_b,
    const float* __restrict__ noise,
    const float* __restrict__ x0,
    u64* __restrict__ buf0,                   // [16][256] packets (t even reads)
    u64* __restrict__ buf1,                   // (t odd reads)
    float* __restrict__ traj,                 // [B][T][HID] (fallback path)
    float* __restrict__ trajWS,               // [T][HID][B] (fast path)
    float* __restrict__ xfinal,
    int* __restrict__ ready,                  // 256 flags, 64B apart (zeroed)
    const float* __restrict__ pre,            // [T][HID][B] or unused
    int use_pre, int use_tws) {
    __shared__ short rlds[16384];             // 32 KB swizzled r
    __shared__ float redw[256];               // [b][w] transposed partials
    __shared__ char lds_pad[57344];           // force 1 block/CU (total ~90 KB)

    const int tid  = threadIdx.x;
    const int j    = blockIdx.x;
    const int w    = tid >> 6;
    const int lane = tid & 63;
    const int quad = lane >> 4;
    const int col  = lane & 15;

    if (j == 0x7fffffff) lds_pad[tid] = 0;    // never true; keeps pad alive

    // ---- W fragments into registers: 32 x short8 = 128 VGPRs.
    //      Lane mapping W[j, i=tile+(l&15), k=(l>>4)*8+e] serves as the
    //      A-operand (m=i) of the swapped MFMA (A/B frag layouts identical).
    short8 wreg[32];
    {
        const short* __restrict__ wsh = (const short*)Wsw;
#pragma unroll
        for (int kk = 0; kk < 8; ++kk)
#pragma unroll
            for (int mt = 0; mt < 4; ++mt)
                wreg[kk * 4 + mt] = *(const short8*)(wsh +
                    ((((size_t)j * 8 + kk) * 16 + (w * 4 + mt)) * 64 + lane) * 8);
    }
    // whh for this thread's 16 i-values: i = (w*4+mt)*16 + quad*4 + rg
    // (folded into MFMA acc init; each wave owns its i-range exclusively)
    float whh16[16];
#pragma unroll
    for (int mt = 0; mt < 4; ++mt)
#pragma unroll
        for (int rg = 0; rg < 4; ++rg)
            whh16[mt * 4 + rg] = w_hh[j * HID + (w * 4 + mt) * 16 + quad * 4 + rg];

    float xb = 0.f;
    if (tid < BSZ) xb = x0[tid * HID + j];

#pragma unroll 1
    for (int t = 0; t < TLEN; ++t) {
        const u64* __restrict__ rcur = (t & 1) ? buf1 : buf0;
        u64* __restrict__ rnxt = (t & 1) ? buf0 : buf1;

        // ---- input term prefetch (independent, overlaps poll) ----
        float extra = 0.f;
        if (tid < BSZ) {
            if (use_pre) {
                extra = pre[((size_t)t * HID + j) * BSZ + tid];
            } else {
                float isum = w_in_b[j];
                const float4* __restrict__ urow =
                    (const float4*)(u + ((size_t)tid * TLEN + t) * INW);
                const float4* __restrict__ wrow = (const float4*)(w_in_w + (size_t)j * INW);
#pragma unroll
                for (int q = 0; q < INW / 4; ++q) {
                    float4 uu = urow[q], ww = wrow[q];
                    isum = fmaf(uu.x, ww.x, isum);
                    isum = fmaf(uu.y, ww.y, isum);
                    isum = fmaf(uu.z, ww.z, isum);
                    isum = fmaf(uu.w, ww.w, isum);
                }
                float nz = noise[((size_t)t * BSZ + tid) * HID + j];
                extra = NOISE_STD * nz + TAU * isum;
            }
        }

        // ---- thread-local wait: flag tid guards exactly this thread's data ----
        if (t > 0) {
            while (__hip_atomic_load(ready + tid * 16, __ATOMIC_RELAXED,
                                     __HIP_MEMORY_SCOPE_AGENT) < t)
                __builtin_amdgcn_s_sleep(1);
            asm volatile("" ::: "memory");
        }

        // ---- load own column (producer tid's output), fill rlds ----
        {
            u64 v[16];
#pragma unroll
            for (int g = 0; g < 16; ++g)
                v[g] = __hip_atomic_load(rcur + g * 256 + tid, __ATOMIC_RELAXED,
                                         __HIP_MEMORY_SCOPE_AGENT);
#pragma unroll
            for (int g = 0; g < 16; ++g)
#pragma unroll
                for (int e = 0; e < 4; ++e)
                    rlds[ridx(4 * g + e, tid)] = (short)(v[g] >> (16 * e));
        }
        __syncthreads();                       // barrier B: rlds complete

        // ---- GEMM (swapped): D[i,b] = w_hh[j,i] + sum_k W[j,i,k] r[b,k] ----
        floatx4 acc[4][4];                     // acc[mt=i-tile][nt=b-tile]
#pragma unroll
        for (int mt = 0; mt < 4; ++mt)
#pragma unroll
            for (int nt = 0; nt < 4; ++nt)
                acc[mt][nt] = (floatx4){whh16[mt * 4 + 0], whh16[mt * 4 + 1],
                                        whh16[mt * 4 + 2], whh16[mt * 4 + 3]};

#pragma unroll
        for (int kk = 0; kk < 8; ++kk) {
            short8 afrag[4];
#pragma unroll
            for (int nt = 0; nt < 4; ++nt)
                afrag[nt] = *(const short8*)&rlds[ridx(nt * 16 + col, kk * 32 + quad * 8)];
#pragma unroll
            for (int mt = 0; mt < 4; ++mt)
#pragma unroll
                for (int nt = 0; nt < 4; ++nt)
                    acc[mt][nt] = __builtin_amdgcn_mfma_f32_16x16x32_bf16(
                        wreg[kk * 4 + mt], afrag[nt], acc[mt][nt], 0, 0, 0);
        }

        // ---- epilogue: part[b] = sum_i r[b,i]*P'[i,b]  (whh already in acc) ----
        // lane (col,quad): acc[mt][nt][rg] = P'[i=(w*4+mt)*16+quad*4+rg][b=nt*16+col]
        float part[4];
#pragma unroll
        for (int nt = 0; nt < 4; ++nt) part[nt] = 0.f;
#pragma unroll
        for (int mt = 0; mt < 4; ++mt) {
            const int ib = (w * 4 + mt) * 16 + quad * 4;
#pragma unroll
            for (int nt = 0; nt < 4; ++nt) {
                const int b = nt * 16 + col;
                shortx4 r4 = *(const shortx4*)&rlds[ridx(b, ib)];
#pragma unroll
                for (int rg = 0; rg < 4; ++rg) {
                    short rs = r4[rg];
                    float rv = __bfloat162float(*(__hip_bfloat16*)&rs);
                    part[nt] = fmaf(rv, acc[mt][nt][rg], part[nt]);
                }
            }
        }
        // reduce across quads only: 8 shuffles
#pragma unroll
        for (int nt = 0; nt < 4; ++nt) {
            part[nt] += __shfl_xor(part[nt], 16, 64);
            part[nt] += __shfl_xor(part[nt], 32, 64);
        }
        // transposed partial store: redw[b*4 + w] -> wave0 reads one float4/b.
        // banks (col*4+w)%32: pairs (col,col+8) share a bank = 2-way = free.
        if (quad == 0) {
#pragma unroll
            for (int nt = 0; nt < 4; ++nt)
                redw[(nt * 16 + col) * 4 + w] = part[nt];
        }
        __syncthreads();                       // barrier C: redw complete

        // ---- wave 0: state update, publish, trajectory ----
        if (w == 0) {
            const int b = lane;
            float4 r4 = *(const float4*)&redw[b * 4];      // one ds_read_b128
            float rec = (r4.x + r4.y) + (r4.z + r4.w);
            float xn = xb + extra + TAU * (rec - xb);
            xb = xn;

            if (t < TLEN - 1) {
                __hip_bfloat16 h = __float2bfloat16(fast_tanh(xn));
                int hs = (int)(*(unsigned short*)&h);
                int src = 4 * (lane & 15);
                u64 pv = (u64)(unsigned)__shfl(hs, src + 0, 64)
                       | ((u64)(unsigned)__shfl(hs, src + 1, 64) << 16)
                       | ((u64)(unsigned)__shfl(hs, src + 2, 64) << 32)
                       | ((u64)(unsigned)__shfl(hs, src + 3, 64) << 48);
                if (lane < 16)
                    __hip_atomic_store(rnxt + (size_t)lane * 256 + j, pv,
                                       __ATOMIC_RELAXED, __HIP_MEMORY_SCOPE_AGENT);
                asm volatile("s_waitcnt vmcnt(0)" ::: "memory");   // drain data
                if (lane == 0)
                    __hip_atomic_store(ready + j * 16, t + 1, __ATOMIC_RELAXED,
                                       __HIP_MEMORY_SCOPE_AGENT);
            }

            if (use_tws) {
                trajWS[((size_t)t * HID + j) * BSZ + b] = xn;      // 256B coalesced
            } else {
                traj[((size_t)b * TLEN + t) * HID + j] = xn;
                if (t == TLEN - 1) xfinal[b * HID + j] = xn;
            }
        }
    }
}

// ---------------------------------------------------------------------------
// fused transpose + output (fast path). block = t.
// ---------------------------------------------------------------------------
__global__ __launch_bounds__(256) void fixup_kernel(
    const float* __restrict__ trajWS,   // [T][HID][B]
    const float* __restrict__ w_out_w,  // [OUT][HID]
    const float* __restrict__ w_out_b,  // [OUT]
    float* __restrict__ traj,           // [B][T][HID]
    float* __restrict__ xfinal,         // [B][HID]
    float* __restrict__ out) {          // [B][T][OUT]
    __shared__ float xv[BSZ * 257];
    __shared__ float wol[OUTW * 257];
    const int t = blockIdx.x, tid = threadIdx.x;

#pragma unroll
    for (int it = 0; it < 16; ++it) {
        int flat = it * 1024 + tid * 4;          // j*64 + b
        float4 v = *(const float4*)(trajWS + (size_t)t * 16384 + flat);
        int jj = flat >> 6, b = flat & 63;
        xv[(b + 0) * 257 + jj] = v.x;
        xv[(b + 1) * 257 + jj] = v.y;
        xv[(b + 2) * 257 + jj] = v.z;
        xv[(b + 3) * 257 + jj] = v.w;
    }
#pragma unroll
    for (int it = 0; it < 8; ++it) {
        int flat = it * 1024 + tid * 4;          // o*256 + h
        float4 v = *(const float4*)(w_out_w + flat);
        int o = flat >> 8, h = flat & 255;
        *(float4*)&wol[o * 257 + h] = v;
    }
    __syncthreads();

    for (int b = 0; b < BSZ; ++b)
        traj[((size_t)b * TLEN + t) * HID + tid] = xv[b * 257 + tid];
    if (t == TLEN - 1)
        for (int b = 0; b < BSZ; ++b)
            xfinal[b * HID + tid] = xv[b * 257 + tid];

    __syncthreads();
#pragma unroll
    for (int it = 0; it < 64; ++it)
        xv[it * 257 + tid] = tanhf(xv[it * 257 + tid]);
    __syncthreads();

    const int o = tid & 31;
    const float bias = w_out_b[o];
#pragma unroll 1
    for (int rep = 0; rep < 8; ++rep) {
        int b = rep * 8 + (tid >> 5);
        float s = bias;
#pragma unroll 8
        for (int h = 0; h < HID; ++h)
            s = fmaf(xv[b * 257 + h], wol[o * 257 + h], s);
        out[((size_t)b * TLEN + t) * OUTW + o] = s;
    }
}

// ---------------------------------------------------------------------------
// fallback output kernel — used when ws too small
// ---------------------------------------------------------------------------
__global__ __launch_bounds__(256) void output_kernel(
    const float* __restrict__ traj, const float* __restrict__ w_out_w,
    const float* __restrict__ w_out_b, float* __restrict__ out) {
    __shared__ float th[8][HID + 1];
    const int bt0 = blockIdx.x * 8;
    const int tid = threadIdx.x;
#pragma unroll
    for (int m = 0; m < 8; ++m) {
        int idx = m * 256 + tid;
        th[idx >> 8][idx & 255] = tanhf(traj[(size_t)bt0 * HID + idx]);
    }
    __syncthreads();
    const int row = tid >> 5, o = tid & 31;
    const float* __restrict__ wrow = w_out_w + (size_t)o * HID;
    float s = w_out_b[o];
#pragma unroll 8
    for (int h = 0; h < HID; ++h) s = fmaf(th[row][h], wrow[h], s);
    out[(size_t)(bt0 + row) * OUTW + o] = s;
}

// ---------------------------------------------------------------------------
extern "C" void kernel_launch(void* const* d_in, const int* in_sizes, int n_in,
                              void* d_out, int out_size, void* d_ws, size_t ws_size,
                              hipStream_t stream) {
    const float* u       = (const float*)d_in[0];
    const float* x0      = (const float*)d_in[1];
    const float* noise   = (const float*)d_in[2];
    const float* w_hh    = (const float*)d_in[3];
    const float* W       = (const float*)d_in[4];
    const float* w_in_w  = (const float*)d_in[5];
    const float* w_in_b  = (const float*)d_in[6];
    const float* w_out_w = (const float*)d_in[7];
    const float* w_out_b = (const float*)d_in[8];

    float* out    = (float*)d_out;                     // [B][T][OUT]
    float* xfinal = out + (size_t)BSZ * TLEN * OUTW;
    float* traj   = xfinal + (size_t)BSZ * HID;

    // ws layout: Wsw 33.5M | buf0 32K | buf1 32K | flags 16K | trajWS 16.7M | pre 16.7M
    char* ws = (char*)d_ws;
    __hip_bfloat16* Wsw = (__hip_bfloat16*)ws;
    u64*   buf0 = (u64*)(ws + 33554432);
    u64*   buf1 = (u64*)(ws + 33587200);
    int*   rdy  = (int*)(ws + 33619968);
    float* tws  = (float*)(ws + 33636352);
    float* pre  = (float*)(ws + 50413568);
    const size_t NEED_TWS = 50413568ull;
    const size_t NEED_PRE = 67190784ull;
    const int use_tws = (ws_size >= NEED_TWS) ? 1 : 0;
    const int use_pre = (ws_size >= NEED_PRE) ? 1 : 0;

    hipMemsetAsync(rdy, 0, 16384, stream);
    swizzle_kernel<<<8192, 256, 0, stream>>>(W, Wsw);
    init_kernel<<<16, 256, 0, stream>>>(x0, buf0);
    if (use_pre)
        pre_kernel<<<TLEN, 256, 0, stream>>>(u, w_in_w, w_in_b, noise, pre);

    persist_kernel<<<256, 256, 0, stream>>>(
        Wsw, w_hh, u, w_in_w, w_in_b, noise, x0,
        buf0, buf1, traj, tws, xfinal, rdy, pre, use_pre, use_tws);

    if (use_tws)
        fixup_kernel<<<TLEN, 256, 0, stream>>>(tws, w_out_w, w_out_b, traj, xfinal, out);
    else
        output_kernel<<<(BSZ * TLEN) / 8, 256, 0, stream>>>(traj, w_out_w, w_out_b, out);
}